// Round 5
// baseline (732.717 us; speedup 1.0000x reference)
//
#include <hip/hip_runtime.h>

// ---------------------------------------------------------------------------
// MultiHeadPooledSelfAttention on gfx950.
// R4: fold pool into projection. pool(proj(x)) = x @ (Wp.Wn)^T + (Wp.bn+bp),
// so one mega GEMM-BT (A=x 4100x512, B=[Wq|Wfq|Wfk|Wfv] 16384x512) produces
// Q, PQ(+emb), PK, PVt(transposed) in one pass. Fused weights via per-head
// transpose + small GEMM; K/V cls rows via tiny dot kernel. Attention keeps
// materialized-S path (nchunk=1, ws>=244MB known from R3 profile).
// ---------------------------------------------------------------------------

typedef unsigned short u16;
typedef __attribute__((ext_vector_type(8))) short short8;   // 8 x bf16
typedef __attribute__((ext_vector_type(4))) float floatx4;
typedef __attribute__((ext_vector_type(4))) unsigned short us4;

__device__ __forceinline__ u16 f2bf(float f) {
  union { float f; unsigned u; } x; x.f = f;
  unsigned r = (x.u + 0x7fffu + ((x.u >> 16) & 1u)) >> 16;
  return (u16)r;
}
__device__ __forceinline__ float bf2f(u16 u) {
  union { unsigned u; float f; } x; x.u = ((unsigned)u) << 16;
  return x.f;
}

__device__ __forceinline__ void gld_lds16(const void* g, void* l) {
  __builtin_amdgcn_global_load_lds(
      (const __attribute__((address_space(1))) void*)g,
      (__attribute__((address_space(3))) void*)l, 16, 0, 0);
}

// ---------------------------------------------------------------------------
struct CvtArgs { const float* src[8]; u16* dst[8]; int n4[8]; };

__global__ __launch_bounds__(256) void cvt_all(CvtArgs a, int total4) {
  int t = blockIdx.x * 256 + threadIdx.x;
  if (t >= total4) return;
#pragma unroll
  for (int s = 0; s < 8; ++s) {
    if (t < a.n4[s]) {
      const float* sp = a.src[s] + (long)t * 4;
      u16* dp = a.dst[s] + (long)t * 4;
      float4 v = *(const float4*)sp;
      dp[0] = f2bf(v.x); dp[1] = f2bf(v.y); dp[2] = f2bf(v.z); dp[3] = f2bf(v.w);
      return;
    }
    t -= a.n4[s];
  }
}

// ---------------------------------------------------------------------------
__global__ __launch_bounds__(256) void emb_kernel(float* __restrict__ e) {
  int t = blockIdx.x * 256 + threadIdx.x;    // < 1024*512
  int c = t & 511, sp = t >> 9;
  int y = sp >> 5, xg = sp & 31;
  int j = c & 127, seg = c >> 7;
  float omega = expf(-(float)j * (9.210340371976184f / 128.f));  // 10000^{-j/128}
  float arg = (float)((seg < 2) ? y : xg) * omega;
  e[t] = (seg & 1) ? cosf(arg) : sinf(arg);
}

// ---------------------------------------------------------------------------
// Fused biases: f*[n*512+oc] = sum_c Wp*[oc][c]*b*[n*512+c] + bp*[oc]  (f32)
// ---------------------------------------------------------------------------
__global__ __launch_bounds__(256) void fuse_bias(
    const float* __restrict__ Wpq, const float* __restrict__ bq, const float* __restrict__ bpq,
    const float* __restrict__ Wpk, const float* __restrict__ bk, const float* __restrict__ bpk,
    const float* __restrict__ Wpv, const float* __restrict__ bv, const float* __restrict__ bpv,
    float* __restrict__ fq, float* __restrict__ fk, float* __restrict__ fv) {
  int t = blockIdx.x * 256 + threadIdx.x;   // < 12288
  int j = t >> 12, o = t & 4095;
  int n = o >> 9, oc = o & 511;
  const float* Wp = (j == 0) ? Wpq : (j == 1) ? Wpk : Wpv;
  const float* b  = (j == 0) ? bq  : (j == 1) ? bk  : bv;
  const float* bp = (j == 0) ? bpq : (j == 1) ? bpk : bpv;
  float s = bp[oc];
  for (int c = 0; c < 512; ++c) s += Wp[oc * 512 + c] * b[n * 512 + c];
  ((j == 0) ? fq : (j == 1) ? fk : fv)[o] = s;
}

// ---------------------------------------------------------------------------
// Per-head transpose of 3 weight matrices (4096x512 -> 24 x 512x512^T).
// WT[(z*512+i)*512+c] = Wsrc(z)[(n*512+c)*512+i],  n=z&7.
// ---------------------------------------------------------------------------
__global__ __launch_bounds__(256) void transpose24(
    const u16* __restrict__ Wq, const u16* __restrict__ Wk,
    const u16* __restrict__ Wv, u16* __restrict__ WT) {
  __shared__ u16 tl[32][33];
  int z = blockIdx.z;
  const u16* W = (z < 8) ? Wq : (z < 16) ? Wk : Wv;
  int n = z & 7;
  int i0 = blockIdx.x * 32, c0 = blockIdx.y * 32;
  int tx = threadIdx.x & 31, ty = threadIdx.x >> 5;   // 32 x 8
#pragma unroll
  for (int r = 0; r < 4; ++r)
    tl[ty + 8 * r][tx] = W[((long)n * 512 + c0 + ty + 8 * r) * 512 + i0 + tx];
  __syncthreads();
#pragma unroll
  for (int r = 0; r < 4; ++r)
    WT[((long)z * 512 + i0 + ty + 8 * r) * 512 + c0 + tx] = tl[tx][ty + 8 * r];
}

// ---------------------------------------------------------------------------
// K/V cls rows: PK[bn][0][ch] = Wk[o].x_cls[b] + bk[o];  PVt[bn][ch][0] likewise.
// ---------------------------------------------------------------------------
__global__ __launch_bounds__(256) void cls_kv(
    const u16* __restrict__ xb, const u16* __restrict__ Wkb, const u16* __restrict__ Wvb,
    const float* __restrict__ bk, const float* __restrict__ bv,
    u16* __restrict__ PK, u16* __restrict__ PVt) {
  __shared__ float xc[4][512];
  int t = threadIdx.x;
#pragma unroll
  for (int q = 0; q < 8; ++q) {
    int idx = q * 256 + t;     // < 2048
    xc[idx >> 9][idx & 511] = bf2f(xb[(long)(idx >> 9) * 1025 * 512 + (idx & 511)]);
  }
  __syncthreads();
  int blk = blockIdx.x;                     // 32 blocks: 16 for K, 16 for V
  bool isV = blk >= 16;
  int o = ((isV ? blk - 16 : blk) * 256 + t);   // 0..4095
  const u16* W = isV ? Wvb : Wkb;
  float a0 = 0, a1 = 0, a2 = 0, a3 = 0;
  for (int k8 = 0; k8 < 64; ++k8) {
    short8 w8 = *(const short8*)(W + (long)o * 512 + k8 * 8);
#pragma unroll
    for (int u = 0; u < 8; ++u) {
      float w = bf2f((u16)w8[u]);
      int k = k8 * 8 + u;
      a0 += xc[0][k] * w; a1 += xc[1][k] * w; a2 += xc[2][k] * w; a3 += xc[3][k] * w;
    }
  }
  int n = o >> 9, ch = o & 511;
  float bias = isV ? bv[o] : bk[o];
  float acc[4] = {a0, a1, a2, a3};
#pragma unroll
  for (int b = 0; b < 4; ++b) {
    float v = acc[b] + bias;
    if (isV) PVt[((long)(b * 8 + n) * 512 + ch) * 1056] = f2bf(v);
    else     PK [((long)(b * 8 + n) * 1025) * 512 + ch] = f2bf(v);
  }
}

// ---------------------------------------------------------------------------
// Softmax: one block per row (heads*1025 rows, 1056 cols, valid 1025).
// ---------------------------------------------------------------------------
__global__ __launch_bounds__(256) void softmax_rows(u16* __restrict__ S) {
  const int t = threadIdx.x;
  u16* row = S + (long)blockIdx.x * 1056;
  us4 p = *(const us4*)(row + t * 4);
  float v[4];
  float mx = -1e30f;
#pragma unroll
  for (int i = 0; i < 4; ++i) { v[i] = bf2f(p[i]); mx = fmaxf(mx, v[i]); }
  float e1024 = (t == 0) ? bf2f(row[1024]) : -1e30f;
  mx = fmaxf(mx, e1024);
  __shared__ float red[4], red2[4];
  for (int o = 32; o > 0; o >>= 1) mx = fmaxf(mx, __shfl_xor(mx, o, 64));
  if ((t & 63) == 0) red[t >> 6] = mx;
  __syncthreads();
  mx = fmaxf(fmaxf(red[0], red[1]), fmaxf(red[2], red[3]));
  float s = 0.f;
#pragma unroll
  for (int i = 0; i < 4; ++i) { v[i] = __expf(v[i] - mx); s += v[i]; }
  e1024 = (t == 0) ? __expf(e1024 - mx) : 0.f;
  s += e1024;
  for (int o = 32; o > 0; o >>= 1) s += __shfl_xor(s, o, 64);
  if ((t & 63) == 0) red2[t >> 6] = s;
  __syncthreads();
  s = red2[0] + red2[1] + red2[2] + red2[3];
  float inv = 1.0f / s;
#pragma unroll
  for (int i = 0; i < 4; ++i) p[i] = f2bf(v[i] * inv);
  *(us4*)(row + t * 4) = p;
  if (t < 8) {
    us4 q;
#pragma unroll
    for (int i = 0; i < 4; ++i) q[i] = 0;
    if (t == 0) q[0] = f2bf(e1024 * inv);
    *(us4*)(row + 1024 + t * 4) = q;
  }
}

// ---------------------------------------------------------------------------
__global__ __launch_bounds__(256) void reduce4(const float* __restrict__ part,
                                               const float* __restrict__ bd,
                                               float* __restrict__ out) {
  int t = blockIdx.x * 256 + threadIdx.x;    // < 524800
  long i = (long)t * 4;
  const long STR = 4100ll * 512;
  float4 a = *(const float4*)(part + i);
  float4 b = *(const float4*)(part + i + STR);
  float4 c = *(const float4*)(part + i + 2 * STR);
  float4 d = *(const float4*)(part + i + 3 * STR);
  float4 bb = *(const float4*)(bd + (int)(i & 511));
  float4 r;
  r.x = a.x + b.x + c.x + d.x + bb.x;
  r.y = a.y + b.y + c.y + d.y + bb.y;
  r.z = a.z + b.z + c.z + d.z + bb.z;
  r.w = a.w + b.w + c.w + d.w + bb.w;
  *(float4*)(out + i) = r;
}

// ---------------------------------------------------------------------------
// GEMM-BT modes:
//  0 MEGA : A=xb(4100x512), B=Wbig(16384x512)=[Wq|Wfq|Wfk|Wfv].
//           sec0 -> Q (+c0), l==0 also PQ cls; sec1 -> PQ spatial (+c1+emb);
//           sec2 -> PK spatial (+c2); sec3 -> PVt spatial transposed (+c3).
//  3 S    : A=PQ[gbz], B=PK[gbz] (1025x512) -> S[z][q][kv]*scale
//  4 O    : A=S[z](1025x1056), B=PVt[gbz](512x1056) -> stk (+Q resid)
//  5 FIN  : A=stk(4100x4096), B=Wd(512x4096), split-K x4 -> f32 partials
//  6 FUSE : A=Wp{q,k,v} by z/8 (512x512), B=WT[z](512x512) -> o0[z]
// ---------------------------------------------------------------------------
struct GP {
  const u16* A; const u16* A2; const u16* A3; const u16* B;
  const float* c0; const float* c1; const float* c2; const float* c3;
  const float* emb; const u16* resid;
  u16* o0; u16* o1; u16* o2; u16* o3;
  float* of; int bz0;
};

template <int MODE>
__global__ __launch_bounds__(256) void gemm_bt(GP g) {
  constexpr int KITER = (MODE == 5) ? 32 : ((MODE == 4) ? 33 : 16);
  __shared__ u16 As[128 * 32];
  __shared__ u16 Bs[128 * 32];
  const int tid = threadIdx.x;
  const int lane = tid & 63;
  const int wv = tid >> 6;
  const int wr = wv >> 1, wc = wv & 1;
  const int mt = blockIdx.y, nt = blockIdx.x;
  const int bz = blockIdx.z;
  const int gbz = g.bz0 + bz;

  const u16* Ap = g.A;
  if constexpr (MODE == 6) Ap = (bz < 8) ? g.A : (bz < 16) ? g.A2 : g.A3;
  const u16* Bp = g.B;

  long a_row[2], b_row[2];
  int kcol[2];
#pragma unroll
  for (int c = 0; c < 2; ++c) {
    int idx = c * 256 + tid;
    int row = idx >> 2, kc = idx & 3;
    kcol[c] = kc * 8;
    {
      int r = mt * 128 + row;
      long off;
      if constexpr (MODE == 0) { r = r < 4099 ? r : 4099; off = (long)r * 512; }
      else if constexpr (MODE == 3) { r = r < 1024 ? r : 1024; off = (long)gbz * 1025 * 512 + (long)r * 512; }
      else if constexpr (MODE == 4) { r = r < 1024 ? r : 1024; off = (long)bz * 1025 * 1056 + (long)r * 1056; }
      else if constexpr (MODE == 5) { r = r < 4099 ? r : 4099; off = (long)r * 4096; }
      else { off = (long)r * 512; }                       // MODE 6
      a_row[c] = off;
    }
    {
      int r = nt * 128 + row;
      long off;
      if constexpr (MODE == 0) off = (long)r * 512;
      else if constexpr (MODE == 3) { r = r < 1024 ? r : 1024; off = (long)gbz * 1025 * 512 + (long)r * 512; }
      else if constexpr (MODE == 4) off = (long)gbz * 512 * 1056 + (long)r * 1056;
      else if constexpr (MODE == 5) off = (long)r * 4096;
      else { off = (long)bz * 262144 + (long)r * 512; }   // MODE 6: WT[z]
      b_row[c] = off;
    }
  }

  floatx4 acc[4][4];
#pragma unroll
  for (int i = 0; i < 4; ++i)
#pragma unroll
    for (int j = 0; j < 4; ++j) acc[i][j] = floatx4{0.f, 0.f, 0.f, 0.f};

  const int lb0 = (wv * 64) * 16;
  const int lb1 = (256 + wv * 64) * 16;
  const int kbase = (MODE == 5) ? bz * 1024 : 0;

  for (int kt = 0; kt < KITER; ++kt) {
    const int k0 = kbase + kt * 32;
    gld_lds16(Ap + a_row[0] + k0 + kcol[0], (char*)As + lb0);
    gld_lds16(Ap + a_row[1] + k0 + kcol[1], (char*)As + lb1);
    gld_lds16(Bp + b_row[0] + k0 + kcol[0], (char*)Bs + lb0);
    gld_lds16(Bp + b_row[1] + k0 + kcol[1], (char*)Bs + lb1);
    __syncthreads();
    short8 af[4], bf[4];
#pragma unroll
    for (int i = 0; i < 4; ++i)
      af[i] = *(const short8*)(As + (wr * 64 + i * 16 + (lane & 15)) * 32 + (lane >> 4) * 8);
#pragma unroll
    for (int j = 0; j < 4; ++j)
      bf[j] = *(const short8*)(Bs + (wc * 64 + j * 16 + (lane & 15)) * 32 + (lane >> 4) * 8);
#pragma unroll
    for (int i = 0; i < 4; ++i)
#pragma unroll
      for (int j = 0; j < 4; ++j)
        acc[i][j] = __builtin_amdgcn_mfma_f32_16x16x32_bf16(af[i], bf[j], acc[i][j], 0, 0, 0);
    __syncthreads();
  }

  // Epilogue: C/D layout col = lane&15, row = (lane>>4)*4 + reg.
  const int ccol = lane & 15;
  const int rgrp = lane >> 4;
#pragma unroll
  for (int i = 0; i < 4; ++i) {
#pragma unroll
    for (int j = 0; j < 4; ++j) {
      const int gcol = nt * 128 + wc * 64 + j * 16 + ccol;
#pragma unroll
      for (int rr = 0; rr < 4; ++rr) {
        const int grow = mt * 128 + wr * 64 + i * 16 + rgrp * 4 + rr;
        float v = acc[i][j][rr];
        if constexpr (MODE == 0) {
          if (grow < 4100) {
            int sec = gcol >> 12;          // block-uniform
            int col = gcol & 4095;
            int n = col >> 9, ch = col & 511;
            int b = grow / 1025;
            int l = grow - b * 1025;
            long bn = b * 8 + n;
            if (sec == 0) {
              u16 r16 = f2bf(v + g.c0[col]);
              g.o0[(bn * 1025 + l) * 512 + ch] = r16;          // Q
              if (l == 0) g.o1[(bn * 1025) * 512 + ch] = r16;  // PQ cls
            } else if (l > 0) {
              int sp = l - 1;
              if (sec == 1)
                g.o1[(bn * 1025 + l) * 512 + ch] = f2bf(v + g.c1[col] + g.emb[sp * 512 + ch]);
              else if (sec == 2)
                g.o2[(bn * 1025 + l) * 512 + ch] = f2bf(v + g.c2[col]);
              else
                g.o3[(bn * 512 + ch) * 1056 + l] = f2bf(v + g.c3[col]);
            }
          }
        } else if constexpr (MODE == 3) {
          if (grow < 1025 && gcol < 1025)
            g.o0[((long)bz * 1025 + grow) * 1056 + gcol] = f2bf(v * 0.04419417382415922f);
        } else if constexpr (MODE == 4) {
          if (grow < 1025) {
            if (grow >= 1) v += bf2f(g.resid[((long)gbz * 1025 + grow) * 512 + gcol]);
            int b = gbz >> 3, n = gbz & 7;
            g.o0[(((long)b * 1025 + grow) * 8 + n) * 512 + gcol] = f2bf(v);
          }
        } else if constexpr (MODE == 5) {
          if (grow < 4100)
            g.of[((long)bz * 4100 + grow) * 512 + gcol] = v;   // partial, no bias
        } else {  // MODE 6
          g.o0[((long)bz * 512 + grow) * 512 + gcol] = f2bf(v);
        }
      }
    }
  }
}

// ---------------------------------------------------------------------------
extern "C" void kernel_launch(void* const* d_in, const int* in_sizes, int n_in,
                              void* d_out, int out_size, void* d_ws, size_t ws_size,
                              hipStream_t stream) {
  const float* x   = (const float*)d_in[0];
  const float* Wq  = (const float*)d_in[1];
  const float* bq  = (const float*)d_in[2];
  const float* Wk  = (const float*)d_in[3];
  const float* bk  = (const float*)d_in[4];
  const float* Wv  = (const float*)d_in[5];
  const float* bv  = (const float*)d_in[6];
  const float* Wpq = (const float*)d_in[7];
  const float* bpq = (const float*)d_in[8];
  const float* Wpk = (const float*)d_in[9];
  const float* bpk = (const float*)d_in[10];
  const float* Wpv = (const float*)d_in[11];
  const float* bpv = (const float*)d_in[12];
  const float* Wd  = (const float*)d_in[13];
  const float* bd  = (const float*)d_in[14];
  float* out = (float*)d_out;

  char* ws = (char*)d_ws;
  size_t off = 0;
  auto alloc = [&](size_t bytes) {
    char* p = ws + off;
    off += (bytes + 255) & ~(size_t)255;
    return p;
  };
  // Persistent through attention:
  u16* Wdb  = (u16*)alloc(4096ull * 512 * 2);
  u16* Q    = (u16*)alloc(32ull * 1025 * 512 * 2);
  u16* PQ   = (u16*)alloc(32ull * 1025 * 512 * 2);   // later: f32 partials (equal size)
  u16* PK   = (u16*)alloc(32ull * 1025 * 512 * 2);   // later: stk (equal size)
  u16* PVt  = (u16*)alloc(32ull * 512 * 1056 * 2);
  float* fbq = (float*)alloc(4096 * 4);
  float* fbk = (float*)alloc(4096 * 4);
  float* fbv = (float*)alloc(4096 * 4);
  // Dead-by-attention group (S aliases from here):
  size_t s_off = off;
  u16* Wbig = (u16*)alloc(16384ull * 512 * 2);   // [Wq | Wfq | Wfk | Wfv]
  u16* xb   = (u16*)alloc(4100ull * 512 * 2);
  u16* Wkb  = (u16*)alloc(4096ull * 512 * 2);
  u16* Wvb  = (u16*)alloc(4096ull * 512 * 2);
  u16* Wpqb = (u16*)alloc(512ull * 512 * 2);
  u16* Wpkb = (u16*)alloc(512ull * 512 * 2);
  u16* Wpvb = (u16*)alloc(512ull * 512 * 2);
  float* embp = (float*)alloc(1024ull * 512 * 4);
  u16* WT   = (u16*)alloc(24ull * 512 * 512 * 2);
  size_t fixed_need = off;
  u16* S = (u16*)(ws + s_off);
  float* part = (float*)PQ;
  (void)in_sizes; (void)n_in; (void)out_size;

  const size_t sbytes = 1025ull * 1056 * 2;
  size_t need1 = s_off + 32ull * sbytes;                 // ~209 MB, 1 chunk
  size_t need4 = s_off + 8ull * sbytes + 4100ull * 4096 * 2;  // 4-chunk + sep stk
  int nchunk;
  u16* stk;
  if (ws_size >= need1)      { nchunk = 1; stk = PK; }   // PK dead before stk write
  else if (ws_size >= need4 && ws_size >= fixed_need) {
    nchunk = 4; stk = (u16*)(ws + s_off + ((8ull * sbytes + 255) & ~(size_t)255));
  } else return;  // clean fail instead of GPU fault
  int hpc = 32 / nchunk;

  // 1) dtype conversions
  CvtArgs ca;
  ca.src[0] = x;   ca.dst[0] = xb;    ca.n4[0] = 4100 * 512 / 4;
  ca.src[1] = Wq;  ca.dst[1] = Wbig;  ca.n4[1] = 4096 * 512 / 4;
  ca.src[2] = Wk;  ca.dst[2] = Wkb;   ca.n4[2] = 4096 * 512 / 4;
  ca.src[3] = Wv;  ca.dst[3] = Wvb;   ca.n4[3] = 4096 * 512 / 4;
  ca.src[4] = Wpq; ca.dst[4] = Wpqb;  ca.n4[4] = 512 * 512 / 4;
  ca.src[5] = Wpk; ca.dst[5] = Wpkb;  ca.n4[5] = 512 * 512 / 4;
  ca.src[6] = Wpv; ca.dst[6] = Wpvb;  ca.n4[6] = 512 * 512 / 4;
  ca.src[7] = Wd;  ca.dst[7] = Wdb;   ca.n4[7] = 512 * 4096 / 4;
  int total4 = 0;
  for (int s = 0; s < 8; ++s) total4 += ca.n4[s];
  cvt_all<<<(total4 + 255) / 256, 256, 0, stream>>>(ca, total4);

  // 2) positional embedding + fused biases
  emb_kernel<<<(1024 * 512) / 256, 256, 0, stream>>>(embp);
  fuse_bias<<<48, 256, 0, stream>>>(Wpq, bq, bpq, Wpk, bk, bpk, Wpv, bv, bpv, fbq, fbk, fbv);

  // 3) per-head transposes + fused-weight GEMMs -> Wbig sections 1..3
  transpose24<<<dim3(16, 16, 24), 256, 0, stream>>>(Wbig, Wkb, Wvb, WT);
  {
    GP g = {};
    g.A = Wpqb; g.A2 = Wpkb; g.A3 = Wpvb; g.B = WT;
    g.o0 = Wbig + 4096ull * 512;
    gemm_bt<6><<<dim3(4, 4, 24), 256, 0, stream>>>(g);
  }

  // 4) mega projection GEMM -> Q, PQ(+emb,+cls), PK(spatial), PVt(spatial)
  {
    GP g = {};
    g.A = xb; g.B = Wbig;
    g.c0 = bq; g.c1 = fbq; g.c2 = fbk; g.c3 = fbv;
    g.emb = embp;
    g.o0 = Q; g.o1 = PQ; g.o2 = PK; g.o3 = PVt;
    gemm_bt<0><<<dim3(128, 33, 1), 256, 0, stream>>>(g);
  }

  // 5) K/V cls rows
  cls_kv<<<32, 256, 0, stream>>>(xb, Wkb, Wvb, bk, bv, PK, PVt);

  // 6) attention: logits -> softmax -> O (+Q resid)
  for (int c = 0; c < nchunk; ++c) {
    GP g3 = {}; g3.A = PQ; g3.B = PK; g3.o0 = S; g3.bz0 = c * hpc;
    gemm_bt<3><<<dim3(9, 9, hpc), 256, 0, stream>>>(g3);
    softmax_rows<<<hpc * 1025, 256, 0, stream>>>(S);
    GP g4 = {}; g4.A = S; g4.B = PVt; g4.resid = Q; g4.o0 = stk; g4.bz0 = c * hpc;
    gemm_bt<4><<<dim3(4, 9, hpc), 256, 0, stream>>>(g4);
  }
  // PQ dead -> f32 partials alias it.

  // 7) final projection, split-K x4 -> partials, then reduce (+bias)
  {
    GP g = {}; g.A = stk; g.B = Wdb; g.of = part;
    gemm_bt<5><<<dim3(4, 33, 4), 256, 0, stream>>>(g);
  }
  reduce4<<<(4100 * 512 / 4 + 255) / 256, 256, 0, stream>>>(part, bd, out);
}